// Round 9
// baseline (568.260 us; speedup 1.0000x reference)
//
#include <hip/hip_runtime.h>
#include <hip/hip_bf16.h>

// x[32768,256] f32, W[256,256], b[256], emb[1024,256]
// d_out: quant[32768*256] | indices[32768] (as float) | loss[1]
//
// Pipeline:
//   k_ee      : ee[n] = sum emb[n]^2 (+ zeroes the compaction counter)
//   k_pack    : emb -> bf16 packed in MFMA-fragment order (for k_screen) AND
//               emb -> fp32 transposed embP4[k4][n] (bit-exact, k_rescoreT).
//   k_wpack   : W -> 3-way bf16 split, packed in MFMA-fragment order.
//   k_proj    : z = x @ W^T + b via 3-way-split bf16 MFMA. 32 tokens/block
//               (1024 blocks -> 4 blocks/CU, fixes grid-capped occupancy);
//               4 waves = column quarters. Per-output acc chain (kb asc,
//               6-MFMA order, same fragment values) identical to the
//               harness-proven kernel -> bit-identical z.
//   k_screen  : bf16 MFMA distance screen -> idx (+4096 flag if top-2 gap
//               < B_S). 32 tokens/block (1024 blocks -> 4 blocks/CU);
//               round-5 validated structure: A from LDS, B ping-pong
//               registers from pemb (no main-loop barriers); wave w owns
//               code sub-block nb=w. Per-(row,code) MFMA chain and fold
//               identical to the validated kernel -> bit-identical scores;
//               epilogue = validated 32-lane shfl top-2 reduce + 4-way
//               multiset combine (order-independent -> identical results).
//   k_compact : ballot+atomic compaction of flagged token ids.
//   k_rescoreT: exact fp32 re-argmin over the worklist (validated chains).
//   k_gather  : quant = emb[idx] (in-place over z), loss partials
//   k_loss    : 1.25 * sum / (T*D)
//
// Numerics: reference dist = fl(fl(zz+ee[n]) - 2*dot) quantized to ulp(~256)
// ~3e-5. Screen score error sigma ~2.7e-5; B_S = 5e-4 >> 8*sigma + 2 ulp, so
// unflagged tokens have a guaranteed-unique exact argmin; flagged tokens get
// the full exact scan — the round-2/3 validated formula.
#define TT 32768
#define DD 256
#define KK 1024
#define B_S 5e-4f

typedef __attribute__((ext_vector_type(8)))  short bf16x8;
typedef __attribute__((ext_vector_type(4)))  short bf16x4s;
typedef __attribute__((ext_vector_type(16))) float f32x16;

static inline __device__ short f2bf(float v) {
    __hip_bfloat16 h = __float2bfloat16(v);
    return __builtin_bit_cast(short, h);
}
static inline __device__ float bf2f(short s) {
    __hip_bfloat16 h = __builtin_bit_cast(__hip_bfloat16, s);
    return __bfloat162float(h);
}

// ---------------------------------------------------------------------------
__global__ void k_ee(const float* __restrict__ emb, float* __restrict__ ee,
                     int* __restrict__ g_nf) {
    if (blockIdx.x == 0 && threadIdx.x == 0) g_nf[0] = 0;
    int n = blockIdx.x * 256 + threadIdx.x;
    if (n >= KK) return;
    const float4* r = (const float4*)(emb + (size_t)n * DD);
    float s = 0.f;
#pragma unroll
    for (int i = 0; i < DD / 4; ++i) {
        float4 v = r[i];
        s += v.x * v.x + v.y * v.y + v.z * v.z + v.w * v.w;
    }
    ee[n] = s;
}

// ---------------------------------------------------------------------------
// Pack emb as bf16 in MFMA-fragment order (pemb) and as fp32 transposed
// float4 blocks (embP4[k4*1024 + n] = emb[n][k4*4 .. +3], bit-exact).
// 16B unit u: lane=u&63, ks=(u>>6)&1, nb=(u>>7)&3, kbi=(u>>9)&7, nc=(u>>12)&7
// holds emb[nc*128 + nb*32 + (lane&31)][kbi*32 + ks*16 + (lane>>5)*8 .. +7]
__global__ void k_pack(const float* __restrict__ emb, short* __restrict__ pemb,
                       float4* __restrict__ embP4) {
    int u = blockIdx.x * 256 + threadIdx.x;
    int lane = u & 63;
    int ks  = (u >> 6) & 1, nb = (u >> 7) & 3;
    int kbi = (u >> 9) & 7, nc = (u >> 12) & 7;
    int n = nc * 128 + nb * 32 + (lane & 31);
    int k = kbi * 32 + ks * 16 + (lane >> 5) * 8;
    const float* src = emb + (size_t)n * DD + k;
    float4 v0 = *(const float4*)(src);
    float4 v1 = *(const float4*)(src + 4);
    bf16x8 hb = { f2bf(v0.x), f2bf(v0.y), f2bf(v0.z), f2bf(v0.w),
                  f2bf(v1.x), f2bf(v1.y), f2bf(v1.z), f2bf(v1.w) };
    *(bf16x8*)(pemb + (size_t)u * 8) = hb;
    embP4[(size_t)(k >> 2) * KK + n]       = v0;
    embP4[(size_t)((k >> 2) + 1) * KK + n] = v1;
}

// ---------------------------------------------------------------------------
// Pack W's 3-way bf16 split in k_proj fragment order. Chunk (kb,s,g,cb,ks)
// = 1KB: lane l holds W-split[s][row = g*128+cb*32+(l&31)]
// [cols kb*32 + ks*16 + (l>>5)*8 .. +7]. Split chain identical to the
// validated in-kernel code -> identical bf16 values.
__global__ void k_wpack(const float* __restrict__ W, short* __restrict__ Wp) {
    int idx = blockIdx.x * 256 + threadIdx.x;   // 8192 units
    int lane = idx & 63;
    int ks = (idx >> 6) & 1, cb = (idx >> 7) & 3;
    int g  = (idx >> 9) & 1, kb = (idx >> 10) & 7;
    int row = g * 128 + cb * 32 + (lane & 31);
    int col = kb * 32 + ks * 16 + (lane >> 5) * 8;
    const float* src = W + (size_t)row * DD + col;
    float4 v0 = *(const float4*)(src);
    float4 v1 = *(const float4*)(src + 4);
    float e[8] = {v0.x, v0.y, v0.z, v0.w, v1.x, v1.y, v1.z, v1.w};
    bf16x8 s1, s2, s3;
#pragma unroll
    for (int q = 0; q < 8; ++q) {
        short h1 = f2bf(e[q]); float r1 = e[q] - bf2f(h1);
        short h2 = f2bf(r1);   float r2 = r1 - bf2f(h2);
        short h3 = f2bf(r2);
        s1[q] = h1; s2[q] = h2; s3[q] = h3;
    }
    // chunk base = (((kb*3+s)*2+g)*4+cb)*2+ks, 512 shorts per chunk
    size_t c0 = ((((size_t)kb * 3 + 0) * 2 + g) * 4 + cb) * 2 + ks;
    size_t c1 = ((((size_t)kb * 3 + 1) * 2 + g) * 4 + cb) * 2 + ks;
    size_t c2 = ((((size_t)kb * 3 + 2) * 2 + g) * 4 + cb) * 2 + ks;
    *(bf16x8*)(Wp + c0 * 512 + lane * 8) = s1;
    *(bf16x8*)(Wp + c1 * 512 + lane * 8) = s2;
    *(bf16x8*)(Wp + c2 * 512 + lane * 8) = s3;
}

// ---------------------------------------------------------------------------
// z = x @ W^T + b. 32 tokens x 256 outs per block; wave w owns cols
// [w*64, w*64+64) (cb in {0,1}). Same fragment values and per-acc MFMA
// order as the harness-proven kernel -> bit-identical z.
#define PW 40   // bf16 row stride for x tiles (80 B: 16B-aligned)

__launch_bounds__(256, 2)
__global__ void k_proj(const float* __restrict__ x, const short* __restrict__ Wp,
                       const float* __restrict__ bias, float* __restrict__ z) {
    __shared__ __align__(16) short Ax[3][32 * PW];    // 7.7 KB
    const int tid = threadIdx.x;
    const int w = tid >> 6, lane = tid & 63;
    const int l31 = lane & 31, h = lane >> 5;
    const int t0 = blockIdx.x * 32;

    f32x16 acc[2];
#pragma unroll
    for (int cb = 0; cb < 2; ++cb)
#pragma unroll
        for (int r = 0; r < 16; ++r) acc[cb][r] = 0.f;

    for (int kb8 = 0; kb8 < 8; ++kb8) {
        __syncthreads();
        // W fragment loads for this kb step (12 x 16B, L2-hot); hide under
        // the x conversion below. Old-chunk coords: g'=w>>1, cb'=(w&1)*2+cb.
        bf16x8 wb[2][2][3];   // [ks][cb][split]
#pragma unroll
        for (int ks = 0; ks < 2; ++ks)
#pragma unroll
            for (int cb = 0; cb < 2; ++cb)
#pragma unroll
                for (int s = 0; s < 3; ++s) {
                    size_t c = ((((size_t)kb8 * 3 + s) * 2 + (w >> 1)) * 4
                                + ((w & 1) * 2 + cb)) * 2 + ks;
                    wb[ks][cb][s] = *(const bf16x8*)(Wp + c * 512 + lane * 8);
                }
        // x tile 32x32 -> 3-way split (validated conversion chain)
        {
            int row = tid >> 3, c4 = tid & 7;
            float4 v = *(const float4*)(x + (size_t)(t0 + row) * DD + kb8 * 32 + c4 * 4);
            float e[4] = {v.x, v.y, v.z, v.w};
            bf16x4s s1, s2, s3;
#pragma unroll
            for (int q = 0; q < 4; ++q) {
                short h1 = f2bf(e[q]); float r1 = e[q] - bf2f(h1);
                short h2 = f2bf(r1);   float r2 = r1 - bf2f(h2);
                short h3 = f2bf(r2);
                s1[q] = h1; s2[q] = h2; s3[q] = h3;
            }
            int a = row * PW + c4 * 4;
            *(bf16x4s*)&Ax[0][a] = s1; *(bf16x4s*)&Ax[1][a] = s2; *(bf16x4s*)&Ax[2][a] = s3;
        }
        __syncthreads();
#pragma unroll
        for (int ks = 0; ks < 2; ++ks) {
            int ao = l31 * PW + ks * 16 + h * 8;
            bf16x8 a1 = *(bf16x8*)&Ax[0][ao];
            bf16x8 a2 = *(bf16x8*)&Ax[1][ao];
            bf16x8 a3 = *(bf16x8*)&Ax[2][ao];
#pragma unroll
            for (int cb = 0; cb < 2; ++cb) {
                bf16x8 b1 = wb[ks][cb][0];
                bf16x8 b2 = wb[ks][cb][1];
                bf16x8 b3 = wb[ks][cb][2];
                // small terms first for accumulation accuracy (validated order)
                acc[cb] = __builtin_amdgcn_mfma_f32_32x32x16_bf16(a1, b3, acc[cb], 0, 0, 0);
                acc[cb] = __builtin_amdgcn_mfma_f32_32x32x16_bf16(a2, b2, acc[cb], 0, 0, 0);
                acc[cb] = __builtin_amdgcn_mfma_f32_32x32x16_bf16(a3, b1, acc[cb], 0, 0, 0);
                acc[cb] = __builtin_amdgcn_mfma_f32_32x32x16_bf16(a1, b2, acc[cb], 0, 0, 0);
                acc[cb] = __builtin_amdgcn_mfma_f32_32x32x16_bf16(a2, b1, acc[cb], 0, 0, 0);
                acc[cb] = __builtin_amdgcn_mfma_f32_32x32x16_bf16(a1, b1, acc[cb], 0, 0, 0);
            }
        }
    }
    // epilogue: C/D layout col=lane&31, row=(r&3)+8*(r>>2)+4*(lane>>5)
#pragma unroll
    for (int cb = 0; cb < 2; ++cb) {
        int col = w * 64 + cb * 32 + l31;
        float bc = bias[col];
#pragma unroll
        for (int r = 0; r < 16; ++r) {
            int row = (r & 3) + 8 * (r >> 2) + 4 * h;
            z[(size_t)(t0 + row) * DD + col] = acc[cb][r] + bc;
        }
    }
}

// ---------------------------------------------------------------------------
// bf16 MFMA screening, 32 tokens/block (1024 blocks -> 4 blocks/CU).
// Round-5 validated structure: A from LDS, B ping-pong registers (no
// main-loop barriers); wave w owns codes n = nc*128 + w*32 + l31.
// Fold and MFMA chains bit-identical to the validated kernel.
#define SW 264   // A_s row stride (bf16 elems)

__launch_bounds__(256, 3)
__global__ void k_screen(const float* __restrict__ z, const short* __restrict__ pemb,
                         const float* __restrict__ ee_g, float* __restrict__ out_idx) {
    __shared__ __align__(16) short A_s[32 * SW];   // 16.5 KB
    __shared__ float ee_s[1024];
    __shared__ float zzs[32];
    __shared__ float r_bv[32][5]; __shared__ int r_bi[32][5]; __shared__ float r_sv[32][5];

    const int tid = threadIdx.x;
    const int w = tid >> 6, lane = tid & 63;
    const int l31 = lane & 31, h = lane >> 5;
    const int t0 = blockIdx.x * 32;

#pragma unroll
    for (int i = 0; i < 4; ++i) ee_s[i * 256 + tid] = ee_g[i * 256 + tid];

    // A init: z tile -> bf16 LDS + exact fp32 zz sums (validated code)
#pragma unroll
    for (int i = 0; i < 8; ++i) {
        int tl = i * 4 + w;
        float4 v = *(const float4*)(z + (size_t)(t0 + tl) * DD + lane * 4);
        float sq = v.x * v.x + v.y * v.y + v.z * v.z + v.w * v.w;
#pragma unroll
        for (int o = 32; o; o >>= 1) sq += __shfl_xor(sq, o);
        if (lane == 0) zzs[tl] = sq;
        bf16x4s hb = {f2bf(v.x), f2bf(v.y), f2bf(v.z), f2bf(v.w)};
        *(bf16x4s*)&A_s[tl * SW + lane * 4] = hb;
    }
    __syncthreads();   // A_s, zzs, ee_s ready — the ONLY barrier before epilogue

    // per-wave B fragment units (code sub-block nb = w)
    const int u0 = ((w * 2 + 0) * 64 + lane) * 8;  // ks0
    const int u1 = ((w * 2 + 1) * 64 + lane) * 8;  // ks1

    // ping-pong B registers
    bf16x8 B0A = *(const bf16x8*)(pemb + u0);
    bf16x8 B1A = *(const bf16x8*)(pemb + u1);
    bf16x8 B0B, B1B;

    float bestv[16], secv[16]; int besti[16];
#pragma unroll
    for (int r = 0; r < 16; ++r) { bestv[r] = 1e30f; secv[r] = 1e30f; besti[r] = 0; }

    f32x16 acc;
    for (int t = 0; t < 64; t += 2) {
        // load tile t+1 into B (t+1 <= 63)
        {
            const short* gt = pemb + (size_t)(t + 1) * 4096;
            B0B = *(const bf16x8*)(gt + u0);
            B1B = *(const bf16x8*)(gt + u1);
        }
        // compute tile t (kbi even; kbi==0 starts a chunk)
        {
            const int kbi = t & 7;
            if (kbi == 0) {
#pragma unroll
                for (int r = 0; r < 16; ++r) acc[r] = 0.f;
            }
            bf16x8 a0 = *(bf16x8*)&A_s[l31 * SW + kbi * 32 + 0 * 16 + h * 8];
            bf16x8 a1 = *(bf16x8*)&A_s[l31 * SW + kbi * 32 + 1 * 16 + h * 8];
            acc = __builtin_amdgcn_mfma_f32_32x32x16_bf16(a0, B0A, acc, 0, 0, 0);
            acc = __builtin_amdgcn_mfma_f32_32x32x16_bf16(a1, B1A, acc, 0, 0, 0);
        }
        // load tile t+2 into A
        if (t < 62) {
            const short* gt = pemb + (size_t)(t + 2) * 4096;
            B0A = *(const bf16x8*)(gt + u0);
            B1A = *(const bf16x8*)(gt + u1);
        }
        // compute tile t+1 (kbi odd; kbi==7 ends a chunk -> fold)
        {
            const int kbi = (t + 1) & 7;
            bf16x8 a0 = *(bf16x8*)&A_s[l31 * SW + kbi * 32 + 0 * 16 + h * 8];
            bf16x8 a1 = *(bf16x8*)&A_s[l31 * SW + kbi * 32 + 1 * 16 + h * 8];
            acc = __builtin_amdgcn_mfma_f32_32x32x16_bf16(a0, B0B, acc, 0, 0, 0);
            acc = __builtin_amdgcn_mfma_f32_32x32x16_bf16(a1, B1B, acc, 0, 0, 0);
            if (kbi == 7) {
                // fold: s = fl(fl(zz+ee) - 2*dot), top-2 + best index (validated)
                const int nc = (t + 1) >> 3;
                const int n = nc * 128 + w * 32 + l31;
                float en = ee_s[n];
#pragma unroll
                for (int r = 0; r < 16; ++r) {
                    int row = (r & 3) + 8 * (r >> 2) + 4 * h;
                    float u = zzs[row] + en;
                    float sc = fmaf(-2.f, acc[r], u);
                    if (sc < bestv[r])      { secv[r] = bestv[r]; bestv[r] = sc; besti[r] = n; }
                    else if (sc < secv[r])  { secv[r] = sc; }
                }
            }
        }
    }

    // cross-lane reduce within each 32-lane half (codes) — verbatim validated
#pragma unroll
    for (int o = 1; o < 32; o <<= 1) {
#pragma unroll
        for (int r = 0; r < 16; ++r) {
            float ov = __shfl_xor(bestv[r], o);
            int   oi = __shfl_xor(besti[r], o);
            float os = __shfl_xor(secv[r], o);
            float mx = fmaxf(bestv[r], ov);
            secv[r] = fminf(fminf(secv[r], os), mx);
            if (ov < bestv[r] || (ov == bestv[r] && oi < besti[r])) { bestv[r] = ov; besti[r] = oi; }
        }
    }
    // per-wave partials -> LDS (lanes with l31==0; both h halves, rows disjoint)
    if (l31 == 0) {
#pragma unroll
        for (int r = 0; r < 16; ++r) {
            int tr = (r & 3) + 8 * (r >> 2) + 4 * h;
            r_bv[tr][w] = bestv[r]; r_bi[tr][w] = besti[r]; r_sv[tr][w] = secv[r];
        }
    }
    __syncthreads();
    // 4-way multiset top-2 combine (exact, order-independent) + flag
    if (tid < 32) {
        float bv = r_bv[tid][0], sv = r_sv[tid][0];
        int   bi = r_bi[tid][0];
#pragma unroll
        for (int ww = 1; ww < 4; ++ww) {
            float v  = r_bv[tid][ww];
            float s2 = r_sv[tid][ww];
            int   i  = r_bi[tid][ww];
            float mx = fmaxf(bv, v);
            sv = fminf(fminf(sv, s2), mx);
            if (v < bv || (v == bv && i < bi)) { bv = v; bi = i; }
        }
        float flag = ((sv - bv) < B_S) ? 4096.0f : 0.0f;
        out_idx[t0 + tid] = (float)bi + flag;
    }
}

// ---------------------------------------------------------------------------
// Compact flagged token ids into a global worklist (order-independent result).
__global__ void k_compact(const float* __restrict__ out_idx, int* __restrict__ g_nf,
                          int* __restrict__ g_list) {
    __shared__ int wbase[4];
    __shared__ int bbase;
    const int tid = threadIdx.x;
    const int t = blockIdx.x * 256 + tid;
    const int wid = tid >> 6, lane = tid & 63;
    bool fl = out_idx[t] >= 4096.0f;
    unsigned long long m = __ballot(fl);
    if (lane == 0) wbase[wid] = __popcll(m);
    __syncthreads();
    if (tid == 0) {
        int s = 0;
#pragma unroll
        for (int i = 0; i < 4; ++i) { int c = wbase[i]; wbase[i] = s; s += c; }
        bbase = atomicAdd(g_nf, s);
    }
    __syncthreads();
    if (fl) {
        int rank = __popcll(m & ((1ull << lane) - 1ull));
        g_list[bbase + wbase[wid] + rank] = t;
    }
}

// ---------------------------------------------------------------------------
// Exact fp32 re-argmin over the worklist, 8 tokens/batch, grid-stride.
// (validated round-5 structure, bit-exact chains)
#define RB 8    // tokens per batch (validated batch size)

__launch_bounds__(256, 2)
__global__ void k_rescoreT(const float* __restrict__ z, const float4* __restrict__ embP4,
                           const float* __restrict__ ee_g, const int* __restrict__ g_nf,
                           const int* __restrict__ g_list, float* __restrict__ out_idx) {
    __shared__ float zrows[RB][256];                 // 8 KB
    __shared__ float zz8[RB];
    __shared__ int   toks[RB];
    __shared__ float rv_s[RB][4]; __shared__ int ri_s[RB][4];
    const int tid = threadIdx.x;
    const int w = tid >> 6, lane = tid & 63;
    const int nf = g_nf[0];

    for (int base = blockIdx.x * RB; base < nf; base += gridDim.x * RB) {
        __syncthreads();   // previous batch fully done (zrows/toks reuse)
        if (tid < RB) toks[tid] = (base + tid < nf) ? g_list[base + tid] : -1;
        __syncthreads();
        // stage z rows (pad slots -> zeros: no stale-LDS reads)
#pragma unroll
        for (int qq = 0; qq < RB; ++qq) {
            int tok = toks[qq];
            zrows[qq][tid] = (tok >= 0) ? z[(size_t)tok * DD + tid] : 0.f;
        }
        __syncthreads();
        // zz — EXACT validated per-row arithmetic (wave w rows w, w+4)
        for (int qq = w; qq < RB; qq += 4) {
            float s = 0.f;
#pragma unroll
            for (int k = 0; k < 4; ++k) { float vv = zrows[qq][lane + 64 * k]; s += vv * vv; }
#pragma unroll
            for (int o = 32; o; o >>= 1) s += __shfl_xor(s, o);
            if (lane == 0) zz8[qq] = s;
        }
        __syncthreads();   // zz8 ready

        // hoisted ee for this thread's 4 codes (same loaded values as before)
        float en4[4];
#pragma unroll
        for (int p = 0; p < 4; ++p) en4[p] = ee_g[p * 256 + tid];

        float d[4][RB];
#pragma unroll
        for (int p = 0; p < 4; ++p)
#pragma unroll
            for (int q = 0; q < RB; ++q) d[p][q] = 0.f;

        // ping-pong buffers: eX = 4 coalesced global float4, zX = 8 LDS bcast
        float4 eA[4], eB[4], zA[RB], zB[RB];
#pragma unroll
        for (int p = 0; p < 4; ++p) eA[p] = embP4[(size_t)0 * KK + p * 256 + tid];
#pragma unroll
        for (int q = 0; q < RB; ++q) zA[q] = *(const float4*)&zrows[q][0];

        for (int k4 = 0; k4 < 64; k4 += 2) {
            // issue k4+1 into B (always valid: k4+1 <= 63)
#pragma unroll
            for (int p = 0; p < 4; ++p) eB[p] = embP4[(size_t)(k4 + 1) * KK + p * 256 + tid];
#pragma unroll
            for (int q = 0; q < RB; ++q) zB[q] = *(const float4*)&zrows[q][(k4 + 1) * 4];
            // compute k4 with A — EXACT chains: k4 ascending, x/y/z/w
#pragma unroll
            for (int p = 0; p < 4; ++p)
#pragma unroll
                for (int q = 0; q < RB; ++q) {
                    d[p][q] = fmaf(eA[p].x, zA[q].x, d[p][q]);
                    d[p][q] = fmaf(eA[p].y, zA[q].y, d[p][q]);
                    d[p][q] = fmaf(eA[p].z, zA[q].z, d[p][q]);
                    d[p][q] = fmaf(eA[p].w, zA[q].w, d[p][q]);
                }
            // issue k4+2 into A (guarded)
            if (k4 < 62) {
#pragma unroll
                for (int p = 0; p < 4; ++p) eA[p] = embP4[(size_t)(k4 + 2) * KK + p * 256 + tid];
#pragma unroll
                for (int q = 0; q < RB; ++q) zA[q] = *(const float4*)&zrows[q][(k4 + 2) * 4];
            }
            // compute k4+1 with B
#pragma unroll
            for (int p = 0; p < 4; ++p)
#pragma unroll
                for (int q = 0; q < RB; ++q) {
                    d[p][q] = fmaf(eB[p].x, zB[q].x, d[p][q]);
                    d[p][q] = fmaf(eB[p].y, zB[q].y, d[p][q]);
                    d[p][q] = fmaf(eB[p].z, zB[q].z, d[p][q]);
                    d[p][q] = fmaf(eB[p].w, zB[q].w, d[p][q]);
                }
        }

        // fold: p ascending (= n ascending per thread), then q — verbatim
        float bv[RB]; int bi[RB];
#pragma unroll
        for (int q = 0; q < RB; ++q) { bv[q] = 1e30f; bi[q] = 0; }
#pragma unroll
        for (int p = 0; p < 4; ++p) {
            const int n = p * 256 + tid;
#pragma unroll
            for (int q = 0; q < RB; ++q) {
                float u = zz8[q] + en4[p];         // fl(zz+ee[n])
                float s = fmaf(-2.f, d[p][q], u);  // fl(u - 2*dot)
                if (s < bv[q]) { bv[q] = s; bi[q] = n; }
            }
        }
        // per-token block reduce: lexicographic (value, index) first-min
        for (int q = 0; q < RB; ++q) {
            float v = bv[q]; int i = bi[q];
#pragma unroll
            for (int o = 1; o < 64; o <<= 1) {
                float ov = __shfl_xor(v, o); int oi = __shfl_xor(i, o);
                if (ov < v || (ov == v && oi < i)) { v = ov; i = oi; }
            }
            if (lane == 0) { rv_s[q][w] = v; ri_s[q][w] = i; }
        }
        __syncthreads();
        if (tid < RB) {
            int tk = toks[tid];
            if (tk >= 0) {
                float fv = rv_s[tid][0]; int fi = ri_s[tid][0];
#pragma unroll
                for (int ww = 1; ww < 4; ++ww) {
                    if (rv_s[tid][ww] < fv || (rv_s[tid][ww] == fv && ri_s[tid][ww] < fi)) {
                        fv = rv_s[tid][ww]; fi = ri_s[tid][ww];
                    }
                }
                out_idx[tk] = (float)fi;
            }
        }
    }
}

// ---------------------------------------------------------------------------
__global__ void k_gather(float* __restrict__ zq, const float* __restrict__ emb,
                         const float* __restrict__ out_idx, float* __restrict__ partial) {
    __shared__ float red[4];
    const int tid = threadIdx.x;
    const int t0 = blockIdx.x * 128;
    const int tl = tid >> 1, part = tid & 1;
    int widx = (int)out_idx[t0 + tl];
    widx = min(max(widx, 0), KK - 1);
    const float* erow = emb + (size_t)widx * DD;
    float* qrow = zq + (size_t)(t0 + tl) * DD;
    float lsum = 0.f;
#pragma unroll
    for (int k = 0; k < 32; ++k) {
        int f = part + 2 * k;
        float4 e  = *(const float4*)(erow + f * 4);
        float4 zv = *(const float4*)(qrow + f * 4);
        float dx = e.x - zv.x, dy = e.y - zv.y, dz = e.z - zv.z, dw = e.w - zv.w;
        lsum += dx * dx + dy * dy + dz * dz + dw * dw;
        *(float4*)(qrow + f * 4) = e;
    }
#pragma unroll
    for (int off = 32; off; off >>= 1) lsum += __shfl_down(lsum, off);
    if ((tid & 63) == 0) red[tid >> 6] = lsum;
    __syncthreads();
    if (tid == 0) partial[blockIdx.x] = red[0] + red[1] + red[2] + red[3];
}

// ---------------------------------------------------------------------------
__global__ void k_loss(const float* __restrict__ partial, float* __restrict__ out_loss) {
    __shared__ float red[4];
    int tid = threadIdx.x;
    float s = partial[tid];
#pragma unroll
    for (int off = 32; off; off >>= 1) s += __shfl_down(s, off);
    if ((tid & 63) == 0) red[tid >> 6] = s;
    __syncthreads();
    if (tid == 0)
        out_loss[0] = (red[0] + red[1] + red[2] + red[3]) * (1.25f / 8388608.0f);
}

// ---------------------------------------------------------------------------
extern "C" void kernel_launch(void* const* d_in, const int* in_sizes, int n_in,
                              void* d_out, int out_size, void* d_ws, size_t ws_size,
                              hipStream_t stream) {
    const float* x   = (const float*)d_in[0];
    const float* W   = (const float*)d_in[1];
    const float* b   = (const float*)d_in[2];
    const float* emb = (const float*)d_in[3];

    float* out   = (float*)d_out;
    float* quant = out;                          // holds z, then quant
    float* oidx  = out + (size_t)TT * DD;
    float* oloss = oidx + TT;

    float* wsf     = (float*)d_ws;
    float* ee      = wsf;                        // [0, 1024)
    float* partial = wsf + 1024;                 // [1024, 1280)
    short* pemb    = (short*)(wsf + 1280);       // 262144 bf16 = 131072 f
    int*   g_nf    = (int*)(wsf + 132352);       // 1 int
    int*   g_list  = (int*)(wsf + 132353);       // 32768 ints
    float4* embP4  = (float4*)(wsf + 165124);    // 65536 float4 = 1 MB
    short* Wp      = (short*)(wsf + 427268);     // 196608 bf16 = 384 KB

    k_ee      <<<KK / 256, 256, 0, stream>>>(emb, ee, g_nf);
    k_pack    <<<128,      256, 0, stream>>>(emb, pemb, embP4);
    k_wpack   <<<32,       256, 0, stream>>>(W, Wp);
    k_proj    <<<TT / 32,  256, 0, stream>>>(x, Wp, b, quant);
    k_screen  <<<TT / 32,  256, 0, stream>>>(quant, pemb, ee, oidx);
    k_compact <<<TT / 256, 256, 0, stream>>>(oidx, g_nf, g_list);
    k_rescoreT<<<512,      256, 0, stream>>>(quant, embP4, ee, g_nf, g_list, oidx);
    k_gather  <<<TT / 128, 256, 0, stream>>>(quant, emb, oidx, partial);
    k_loss    <<<1,        256, 0, stream>>>(partial, oloss);
}

// Round 10
// 365.052 us; speedup vs baseline: 1.5567x; 1.5567x over previous
//
#include <hip/hip_runtime.h>
#include <hip/hip_bf16.h>

// x[32768,256] f32, W[256,256], b[256], emb[1024,256]
// d_out: quant[32768*256] | indices[32768] (as float) | loss[1]
//
// Pipeline:
//   k_ee      : ee[n] = sum emb[n]^2 (+ zeroes the compaction counter)
//   k_pack    : emb -> bf16 packed in MFMA-fragment order (for k_screen) AND
//               emb -> fp32 transposed embP4[k4][n] (bit-exact, k_rescoreT).
//   k_wpack   : W -> 3-way bf16 split, packed in MFMA-fragment order.
//   k_proj    : z = x @ W^T + b via 3-way-split bf16 MFMA. 32 tokens/block
//               (1024 blocks -> 4 blocks/CU); 4 waves = column quarters.
//               Per-output acc chain identical to the harness-proven kernel
//               -> bit-identical z. (Round-9 code, harness-PASSED.)
//   k_screen  : bf16 MFMA distance screen -> idx (+4096 flag if top-2 gap
//               < B_S). 32 tokens/block; round-5 validated structure:
//               A from LDS, B ping-pong registers (no main-loop barriers);
//               wave w owns code sub-block nb=w. Scores bit-identical.
//               ROUND-10 CHANGE: launch_bounds (256,3) -> (256,2). The
//               (256,3) cap split the unified reg file and spilled the
//               top-2 arrays to scratch (602 MB writes/dispatch). At
//               (256,2) the state fits in 128 VGPRs (round-5 precedent)
//               and 4 blocks/CU are resident via the 128-VGPR budget.
//   k_compact : ballot+atomic compaction of flagged token ids.
//   k_rescoreT: exact fp32 re-argmin over the worklist (validated chains).
//   k_gather  : quant = emb[idx] (in-place over z), loss partials
//   k_loss    : 1.25 * sum / (T*D)
//
// Numerics: reference dist = fl(fl(zz+ee[n]) - 2*dot) quantized to ulp(~256)
// ~3e-5. Screen score error sigma ~2.7e-5; B_S = 5e-4 >> 8*sigma + 2 ulp, so
// unflagged tokens have a guaranteed-unique exact argmin; flagged tokens get
// the full exact scan — the round-2/3 validated formula.
#define TT 32768
#define DD 256
#define KK 1024
#define B_S 5e-4f

typedef __attribute__((ext_vector_type(8)))  short bf16x8;
typedef __attribute__((ext_vector_type(4)))  short bf16x4s;
typedef __attribute__((ext_vector_type(16))) float f32x16;

static inline __device__ short f2bf(float v) {
    __hip_bfloat16 h = __float2bfloat16(v);
    return __builtin_bit_cast(short, h);
}
static inline __device__ float bf2f(short s) {
    __hip_bfloat16 h = __builtin_bit_cast(__hip_bfloat16, s);
    return __bfloat162float(h);
}

// ---------------------------------------------------------------------------
__global__ void k_ee(const float* __restrict__ emb, float* __restrict__ ee,
                     int* __restrict__ g_nf) {
    if (blockIdx.x == 0 && threadIdx.x == 0) g_nf[0] = 0;
    int n = blockIdx.x * 256 + threadIdx.x;
    if (n >= KK) return;
    const float4* r = (const float4*)(emb + (size_t)n * DD);
    float s = 0.f;
#pragma unroll
    for (int i = 0; i < DD / 4; ++i) {
        float4 v = r[i];
        s += v.x * v.x + v.y * v.y + v.z * v.z + v.w * v.w;
    }
    ee[n] = s;
}

// ---------------------------------------------------------------------------
// Pack emb as bf16 in MFMA-fragment order (pemb) and as fp32 transposed
// float4 blocks (embP4[k4*1024 + n] = emb[n][k4*4 .. +3], bit-exact).
// 16B unit u: lane=u&63, ks=(u>>6)&1, nb=(u>>7)&3, kbi=(u>>9)&7, nc=(u>>12)&7
// holds emb[nc*128 + nb*32 + (lane&31)][kbi*32 + ks*16 + (lane>>5)*8 .. +7]
__global__ void k_pack(const float* __restrict__ emb, short* __restrict__ pemb,
                       float4* __restrict__ embP4) {
    int u = blockIdx.x * 256 + threadIdx.x;
    int lane = u & 63;
    int ks  = (u >> 6) & 1, nb = (u >> 7) & 3;
    int kbi = (u >> 9) & 7, nc = (u >> 12) & 7;
    int n = nc * 128 + nb * 32 + (lane & 31);
    int k = kbi * 32 + ks * 16 + (lane >> 5) * 8;
    const float* src = emb + (size_t)n * DD + k;
    float4 v0 = *(const float4*)(src);
    float4 v1 = *(const float4*)(src + 4);
    bf16x8 hb = { f2bf(v0.x), f2bf(v0.y), f2bf(v0.z), f2bf(v0.w),
                  f2bf(v1.x), f2bf(v1.y), f2bf(v1.z), f2bf(v1.w) };
    *(bf16x8*)(pemb + (size_t)u * 8) = hb;
    embP4[(size_t)(k >> 2) * KK + n]       = v0;
    embP4[(size_t)((k >> 2) + 1) * KK + n] = v1;
}

// ---------------------------------------------------------------------------
// Pack W's 3-way bf16 split in k_proj fragment order. Chunk (kb,s,g,cb,ks)
// = 1KB: lane l holds W-split[s][row = g*128+cb*32+(l&31)]
// [cols kb*32 + ks*16 + (l>>5)*8 .. +7]. Split chain identical to the
// validated in-kernel code -> identical bf16 values.
__global__ void k_wpack(const float* __restrict__ W, short* __restrict__ Wp) {
    int idx = blockIdx.x * 256 + threadIdx.x;   // 8192 units
    int lane = idx & 63;
    int ks = (idx >> 6) & 1, cb = (idx >> 7) & 3;
    int g  = (idx >> 9) & 1, kb = (idx >> 10) & 7;
    int row = g * 128 + cb * 32 + (lane & 31);
    int col = kb * 32 + ks * 16 + (lane >> 5) * 8;
    const float* src = W + (size_t)row * DD + col;
    float4 v0 = *(const float4*)(src);
    float4 v1 = *(const float4*)(src + 4);
    float e[8] = {v0.x, v0.y, v0.z, v0.w, v1.x, v1.y, v1.z, v1.w};
    bf16x8 s1, s2, s3;
#pragma unroll
    for (int q = 0; q < 8; ++q) {
        short h1 = f2bf(e[q]); float r1 = e[q] - bf2f(h1);
        short h2 = f2bf(r1);   float r2 = r1 - bf2f(h2);
        short h3 = f2bf(r2);
        s1[q] = h1; s2[q] = h2; s3[q] = h3;
    }
    // chunk base = (((kb*3+s)*2+g)*4+cb)*2+ks, 512 shorts per chunk
    size_t c0 = ((((size_t)kb * 3 + 0) * 2 + g) * 4 + cb) * 2 + ks;
    size_t c1 = ((((size_t)kb * 3 + 1) * 2 + g) * 4 + cb) * 2 + ks;
    size_t c2 = ((((size_t)kb * 3 + 2) * 2 + g) * 4 + cb) * 2 + ks;
    *(bf16x8*)(Wp + c0 * 512 + lane * 8) = s1;
    *(bf16x8*)(Wp + c1 * 512 + lane * 8) = s2;
    *(bf16x8*)(Wp + c2 * 512 + lane * 8) = s3;
}

// ---------------------------------------------------------------------------
// z = x @ W^T + b. 32 tokens x 256 outs per block; wave w owns cols
// [w*64, w*64+64) (cb in {0,1}). Same fragment values and per-acc MFMA
// order as the harness-proven kernel -> bit-identical z.
#define PW 40   // bf16 row stride for x tiles (80 B: 16B-aligned)

__launch_bounds__(256, 2)
__global__ void k_proj(const float* __restrict__ x, const short* __restrict__ Wp,
                       const float* __restrict__ bias, float* __restrict__ z) {
    __shared__ __align__(16) short Ax[3][32 * PW];    // 7.7 KB
    const int tid = threadIdx.x;
    const int w = tid >> 6, lane = tid & 63;
    const int l31 = lane & 31, h = lane >> 5;
    const int t0 = blockIdx.x * 32;

    f32x16 acc[2];
#pragma unroll
    for (int cb = 0; cb < 2; ++cb)
#pragma unroll
        for (int r = 0; r < 16; ++r) acc[cb][r] = 0.f;

    for (int kb8 = 0; kb8 < 8; ++kb8) {
        __syncthreads();
        // W fragment loads for this kb step (12 x 16B, L2-hot); hide under
        // the x conversion below. Old-chunk coords: g'=w>>1, cb'=(w&1)*2+cb.
        bf16x8 wb[2][2][3];   // [ks][cb][split]
#pragma unroll
        for (int ks = 0; ks < 2; ++ks)
#pragma unroll
            for (int cb = 0; cb < 2; ++cb)
#pragma unroll
                for (int s = 0; s < 3; ++s) {
                    size_t c = ((((size_t)kb8 * 3 + s) * 2 + (w >> 1)) * 4
                                + ((w & 1) * 2 + cb)) * 2 + ks;
                    wb[ks][cb][s] = *(const bf16x8*)(Wp + c * 512 + lane * 8);
                }
        // x tile 32x32 -> 3-way split (validated conversion chain)
        {
            int row = tid >> 3, c4 = tid & 7;
            float4 v = *(const float4*)(x + (size_t)(t0 + row) * DD + kb8 * 32 + c4 * 4);
            float e[4] = {v.x, v.y, v.z, v.w};
            bf16x4s s1, s2, s3;
#pragma unroll
            for (int q = 0; q < 4; ++q) {
                short h1 = f2bf(e[q]); float r1 = e[q] - bf2f(h1);
                short h2 = f2bf(r1);   float r2 = r1 - bf2f(h2);
                short h3 = f2bf(r2);
                s1[q] = h1; s2[q] = h2; s3[q] = h3;
            }
            int a = row * PW + c4 * 4;
            *(bf16x4s*)&Ax[0][a] = s1; *(bf16x4s*)&Ax[1][a] = s2; *(bf16x4s*)&Ax[2][a] = s3;
        }
        __syncthreads();
#pragma unroll
        for (int ks = 0; ks < 2; ++ks) {
            int ao = l31 * PW + ks * 16 + h * 8;
            bf16x8 a1 = *(bf16x8*)&Ax[0][ao];
            bf16x8 a2 = *(bf16x8*)&Ax[1][ao];
            bf16x8 a3 = *(bf16x8*)&Ax[2][ao];
#pragma unroll
            for (int cb = 0; cb < 2; ++cb) {
                bf16x8 b1 = wb[ks][cb][0];
                bf16x8 b2 = wb[ks][cb][1];
                bf16x8 b3 = wb[ks][cb][2];
                // small terms first for accumulation accuracy (validated order)
                acc[cb] = __builtin_amdgcn_mfma_f32_32x32x16_bf16(a1, b3, acc[cb], 0, 0, 0);
                acc[cb] = __builtin_amdgcn_mfma_f32_32x32x16_bf16(a2, b2, acc[cb], 0, 0, 0);
                acc[cb] = __builtin_amdgcn_mfma_f32_32x32x16_bf16(a3, b1, acc[cb], 0, 0, 0);
                acc[cb] = __builtin_amdgcn_mfma_f32_32x32x16_bf16(a1, b2, acc[cb], 0, 0, 0);
                acc[cb] = __builtin_amdgcn_mfma_f32_32x32x16_bf16(a2, b1, acc[cb], 0, 0, 0);
                acc[cb] = __builtin_amdgcn_mfma_f32_32x32x16_bf16(a1, b1, acc[cb], 0, 0, 0);
            }
        }
    }
    // epilogue: C/D layout col=lane&31, row=(r&3)+8*(r>>2)+4*(lane>>5)
#pragma unroll
    for (int cb = 0; cb < 2; ++cb) {
        int col = w * 64 + cb * 32 + l31;
        float bc = bias[col];
#pragma unroll
        for (int r = 0; r < 16; ++r) {
            int row = (r & 3) + 8 * (r >> 2) + 4 * h;
            z[(size_t)(t0 + row) * DD + col] = acc[cb][r] + bc;
        }
    }
}

// ---------------------------------------------------------------------------
// bf16 MFMA screening, 32 tokens/block (1024 blocks). Round-5 validated
// structure: A from LDS, B ping-pong registers (no main-loop barriers);
// wave w owns codes n = nc*128 + w*32 + l31. Fold and MFMA chains
// bit-identical to the validated kernel. launch_bounds (256,2): 128-VGPR
// budget (round-5 precedent, no spills) -> 4 blocks/CU resident.
#define SW 264   // A_s row stride (bf16 elems)

__launch_bounds__(256, 2)
__global__ void k_screen(const float* __restrict__ z, const short* __restrict__ pemb,
                         const float* __restrict__ ee_g, float* __restrict__ out_idx) {
    __shared__ __align__(16) short A_s[32 * SW];   // 16.5 KB
    __shared__ float ee_s[1024];
    __shared__ float zzs[32];
    __shared__ float r_bv[32][5]; __shared__ int r_bi[32][5]; __shared__ float r_sv[32][5];

    const int tid = threadIdx.x;
    const int w = tid >> 6, lane = tid & 63;
    const int l31 = lane & 31, h = lane >> 5;
    const int t0 = blockIdx.x * 32;

#pragma unroll
    for (int i = 0; i < 4; ++i) ee_s[i * 256 + tid] = ee_g[i * 256 + tid];

    // A init: z tile -> bf16 LDS + exact fp32 zz sums (validated code)
#pragma unroll
    for (int i = 0; i < 8; ++i) {
        int tl = i * 4 + w;
        float4 v = *(const float4*)(z + (size_t)(t0 + tl) * DD + lane * 4);
        float sq = v.x * v.x + v.y * v.y + v.z * v.z + v.w * v.w;
#pragma unroll
        for (int o = 32; o; o >>= 1) sq += __shfl_xor(sq, o);
        if (lane == 0) zzs[tl] = sq;
        bf16x4s hb = {f2bf(v.x), f2bf(v.y), f2bf(v.z), f2bf(v.w)};
        *(bf16x4s*)&A_s[tl * SW + lane * 4] = hb;
    }
    __syncthreads();   // A_s, zzs, ee_s ready — the ONLY barrier before epilogue

    // per-wave B fragment units (code sub-block nb = w)
    const int u0 = ((w * 2 + 0) * 64 + lane) * 8;  // ks0
    const int u1 = ((w * 2 + 1) * 64 + lane) * 8;  // ks1

    // ping-pong B registers
    bf16x8 B0A = *(const bf16x8*)(pemb + u0);
    bf16x8 B1A = *(const bf16x8*)(pemb + u1);
    bf16x8 B0B, B1B;

    float bestv[16], secv[16]; int besti[16];
#pragma unroll
    for (int r = 0; r < 16; ++r) { bestv[r] = 1e30f; secv[r] = 1e30f; besti[r] = 0; }

    f32x16 acc;
    for (int t = 0; t < 64; t += 2) {
        // load tile t+1 into B (t+1 <= 63)
        {
            const short* gt = pemb + (size_t)(t + 1) * 4096;
            B0B = *(const bf16x8*)(gt + u0);
            B1B = *(const bf16x8*)(gt + u1);
        }
        // compute tile t (kbi even; kbi==0 starts a chunk)
        {
            const int kbi = t & 7;
            if (kbi == 0) {
#pragma unroll
                for (int r = 0; r < 16; ++r) acc[r] = 0.f;
            }
            bf16x8 a0 = *(bf16x8*)&A_s[l31 * SW + kbi * 32 + 0 * 16 + h * 8];
            bf16x8 a1 = *(bf16x8*)&A_s[l31 * SW + kbi * 32 + 1 * 16 + h * 8];
            acc = __builtin_amdgcn_mfma_f32_32x32x16_bf16(a0, B0A, acc, 0, 0, 0);
            acc = __builtin_amdgcn_mfma_f32_32x32x16_bf16(a1, B1A, acc, 0, 0, 0);
        }
        // load tile t+2 into A
        if (t < 62) {
            const short* gt = pemb + (size_t)(t + 2) * 4096;
            B0A = *(const bf16x8*)(gt + u0);
            B1A = *(const bf16x8*)(gt + u1);
        }
        // compute tile t+1 (kbi odd; kbi==7 ends a chunk -> fold)
        {
            const int kbi = (t + 1) & 7;
            bf16x8 a0 = *(bf16x8*)&A_s[l31 * SW + kbi * 32 + 0 * 16 + h * 8];
            bf16x8 a1 = *(bf16x8*)&A_s[l31 * SW + kbi * 32 + 1 * 16 + h * 8];
            acc = __builtin_amdgcn_mfma_f32_32x32x16_bf16(a0, B0B, acc, 0, 0, 0);
            acc = __builtin_amdgcn_mfma_f32_32x32x16_bf16(a1, B1B, acc, 0, 0, 0);
            if (kbi == 7) {
                // fold: s = fl(fl(zz+ee) - 2*dot), top-2 + best index (validated)
                const int nc = (t + 1) >> 3;
                const int n = nc * 128 + w * 32 + l31;
                float en = ee_s[n];
#pragma unroll
                for (int r = 0; r < 16; ++r) {
                    int row = (r & 3) + 8 * (r >> 2) + 4 * h;
                    float u = zzs[row] + en;
                    float sc = fmaf(-2.f, acc[r], u);
                    if (sc < bestv[r])      { secv[r] = bestv[r]; bestv[r] = sc; besti[r] = n; }
                    else if (sc < secv[r])  { secv[r] = sc; }
                }
            }
        }
    }

    // cross-lane reduce within each 32-lane half (codes) — verbatim validated
#pragma unroll
    for (int o = 1; o < 32; o <<= 1) {
#pragma unroll
        for (int r = 0; r < 16; ++r) {
            float ov = __shfl_xor(bestv[r], o);
            int   oi = __shfl_xor(besti[r], o);
            float os = __shfl_xor(secv[r], o);
            float mx = fmaxf(bestv[r], ov);
            secv[r] = fminf(fminf(secv[r], os), mx);
            if (ov < bestv[r] || (ov == bestv[r] && oi < besti[r])) { bestv[r] = ov; besti[r] = oi; }
        }
    }
    // per-wave partials -> LDS (lanes with l31==0; both h halves, rows disjoint)
    if (l31 == 0) {
#pragma unroll
        for (int r = 0; r < 16; ++r) {
            int tr = (r & 3) + 8 * (r >> 2) + 4 * h;
            r_bv[tr][w] = bestv[r]; r_bi[tr][w] = besti[r]; r_sv[tr][w] = secv[r];
        }
    }
    __syncthreads();
    // 4-way multiset top-2 combine (exact, order-independent) + flag
    if (tid < 32) {
        float bv = r_bv[tid][0], sv = r_sv[tid][0];
        int   bi = r_bi[tid][0];
#pragma unroll
        for (int ww = 1; ww < 4; ++ww) {
            float v  = r_bv[tid][ww];
            float s2 = r_sv[tid][ww];
            int   i  = r_bi[tid][ww];
            float mx = fmaxf(bv, v);
            sv = fminf(fminf(sv, s2), mx);
            if (v < bv || (v == bv && i < bi)) { bv = v; bi = i; }
        }
        float flag = ((sv - bv) < B_S) ? 4096.0f : 0.0f;
        out_idx[t0 + tid] = (float)bi + flag;
    }
}

// ---------------------------------------------------------------------------
// Compact flagged token ids into a global worklist (order-independent result).
__global__ void k_compact(const float* __restrict__ out_idx, int* __restrict__ g_nf,
                          int* __restrict__ g_list) {
    __shared__ int wbase[4];
    __shared__ int bbase;
    const int tid = threadIdx.x;
    const int t = blockIdx.x * 256 + tid;
    const int wid = tid >> 6, lane = tid & 63;
    bool fl = out_idx[t] >= 4096.0f;
    unsigned long long m = __ballot(fl);
    if (lane == 0) wbase[wid] = __popcll(m);
    __syncthreads();
    if (tid == 0) {
        int s = 0;
#pragma unroll
        for (int i = 0; i < 4; ++i) { int c = wbase[i]; wbase[i] = s; s += c; }
        bbase = atomicAdd(g_nf, s);
    }
    __syncthreads();
    if (fl) {
        int rank = __popcll(m & ((1ull << lane) - 1ull));
        g_list[bbase + wbase[wid] + rank] = t;
    }
}

// ---------------------------------------------------------------------------
// Exact fp32 re-argmin over the worklist, 8 tokens/batch, grid-stride.
// (validated round-5 structure, bit-exact chains)
#define RB 8    // tokens per batch (validated batch size)

__launch_bounds__(256, 2)
__global__ void k_rescoreT(const float* __restrict__ z, const float4* __restrict__ embP4,
                           const float* __restrict__ ee_g, const int* __restrict__ g_nf,
                           const int* __restrict__ g_list, float* __restrict__ out_idx) {
    __shared__ float zrows[RB][256];                 // 8 KB
    __shared__ float zz8[RB];
    __shared__ int   toks[RB];
    __shared__ float rv_s[RB][4]; __shared__ int ri_s[RB][4];
    const int tid = threadIdx.x;
    const int w = tid >> 6, lane = tid & 63;
    const int nf = g_nf[0];

    for (int base = blockIdx.x * RB; base < nf; base += gridDim.x * RB) {
        __syncthreads();   // previous batch fully done (zrows/toks reuse)
        if (tid < RB) toks[tid] = (base + tid < nf) ? g_list[base + tid] : -1;
        __syncthreads();
        // stage z rows (pad slots -> zeros: no stale-LDS reads)
#pragma unroll
        for (int qq = 0; qq < RB; ++qq) {
            int tok = toks[qq];
            zrows[qq][tid] = (tok >= 0) ? z[(size_t)tok * DD + tid] : 0.f;
        }
        __syncthreads();
        // zz — EXACT validated per-row arithmetic (wave w rows w, w+4)
        for (int qq = w; qq < RB; qq += 4) {
            float s = 0.f;
#pragma unroll
            for (int k = 0; k < 4; ++k) { float vv = zrows[qq][lane + 64 * k]; s += vv * vv; }
#pragma unroll
            for (int o = 32; o; o >>= 1) s += __shfl_xor(s, o);
            if (lane == 0) zz8[qq] = s;
        }
        __syncthreads();   // zz8 ready

        // hoisted ee for this thread's 4 codes (same loaded values as before)
        float en4[4];
#pragma unroll
        for (int p = 0; p < 4; ++p) en4[p] = ee_g[p * 256 + tid];

        float d[4][RB];
#pragma unroll
        for (int p = 0; p < 4; ++p)
#pragma unroll
            for (int q = 0; q < RB; ++q) d[p][q] = 0.f;

        // ping-pong buffers: eX = 4 coalesced global float4, zX = 8 LDS bcast
        float4 eA[4], eB[4], zA[RB], zB[RB];
#pragma unroll
        for (int p = 0; p < 4; ++p) eA[p] = embP4[(size_t)0 * KK + p * 256 + tid];
#pragma unroll
        for (int q = 0; q < RB; ++q) zA[q] = *(const float4*)&zrows[q][0];

        for (int k4 = 0; k4 < 64; k4 += 2) {
            // issue k4+1 into B (always valid: k4+1 <= 63)
#pragma unroll
            for (int p = 0; p < 4; ++p) eB[p] = embP4[(size_t)(k4 + 1) * KK + p * 256 + tid];
#pragma unroll
            for (int q = 0; q < RB; ++q) zB[q] = *(const float4*)&zrows[q][(k4 + 1) * 4];
            // compute k4 with A — EXACT chains: k4 ascending, x/y/z/w
#pragma unroll
            for (int p = 0; p < 4; ++p)
#pragma unroll
                for (int q = 0; q < RB; ++q) {
                    d[p][q] = fmaf(eA[p].x, zA[q].x, d[p][q]);
                    d[p][q] = fmaf(eA[p].y, zA[q].y, d[p][q]);
                    d[p][q] = fmaf(eA[p].z, zA[q].z, d[p][q]);
                    d[p][q] = fmaf(eA[p].w, zA[q].w, d[p][q]);
                }
            // issue k4+2 into A (guarded)
            if (k4 < 62) {
#pragma unroll
                for (int p = 0; p < 4; ++p) eA[p] = embP4[(size_t)(k4 + 2) * KK + p * 256 + tid];
#pragma unroll
                for (int q = 0; q < RB; ++q) zA[q] = *(const float4*)&zrows[q][(k4 + 2) * 4];
            }
            // compute k4+1 with B
#pragma unroll
            for (int p = 0; p < 4; ++p)
#pragma unroll
                for (int q = 0; q < RB; ++q) {
                    d[p][q] = fmaf(eB[p].x, zB[q].x, d[p][q]);
                    d[p][q] = fmaf(eB[p].y, zB[q].y, d[p][q]);
                    d[p][q] = fmaf(eB[p].z, zB[q].z, d[p][q]);
                    d[p][q] = fmaf(eB[p].w, zB[q].w, d[p][q]);
                }
        }

        // fold: p ascending (= n ascending per thread), then q — verbatim
        float bv[RB]; int bi[RB];
#pragma unroll
        for (int q = 0; q < RB; ++q) { bv[q] = 1e30f; bi[q] = 0; }
#pragma unroll
        for (int p = 0; p < 4; ++p) {
            const int n = p * 256 + tid;
#pragma unroll
            for (int q = 0; q < RB; ++q) {
                float u = zz8[q] + en4[p];         // fl(zz+ee[n])
                float s = fmaf(-2.f, d[p][q], u);  // fl(u - 2*dot)
                if (s < bv[q]) { bv[q] = s; bi[q] = n; }
            }
        }
        // per-token block reduce: lexicographic (value, index) first-min
        for (int q = 0; q < RB; ++q) {
            float v = bv[q]; int i = bi[q];
#pragma unroll
            for (int o = 1; o < 64; o <<= 1) {
                float ov = __shfl_xor(v, o); int oi = __shfl_xor(i, o);
                if (ov < v || (ov == v && oi < i)) { v = ov; i = oi; }
            }
            if (lane == 0) { rv_s[q][w] = v; ri_s[q][w] = i; }
        }
        __syncthreads();
        if (tid < RB) {
            int tk = toks[tid];
            if (tk >= 0) {
                float fv = rv_s[tid][0]; int fi = ri_s[tid][0];
#pragma unroll
                for (int ww = 1; ww < 4; ++ww) {
                    if (rv_s[tid][ww] < fv || (rv_s[tid][ww] == fv && ri_s[tid][ww] < fi)) {
                        fv = rv_s[tid][ww]; fi = ri_s[tid][ww];
                    }
                }
                out_idx[tk] = (float)fi;
            }
        }
    }
}

// ---------------------------------------------------------------------------
__global__ void k_gather(float* __restrict__ zq, const float* __restrict__ emb,
                         const float* __restrict__ out_idx, float* __restrict__ partial) {
    __shared__ float red[4];
    const int tid = threadIdx.x;
    const int t0 = blockIdx.x * 128;
    const int tl = tid >> 1, part = tid & 1;
    int widx = (int)out_idx[t0 + tl];
    widx = min(max(widx, 0), KK - 1);
    const float* erow = emb + (size_t)widx * DD;
    float* qrow = zq + (size_t)(t0 + tl) * DD;
    float lsum = 0.f;
#pragma unroll
    for (int k = 0; k < 32; ++k) {
        int f = part + 2 * k;
        float4 e  = *(const float4*)(erow + f * 4);
        float4 zv = *(const float4*)(qrow + f * 4);
        float dx = e.x - zv.x, dy = e.y - zv.y, dz = e.z - zv.z, dw = e.w - zv.w;
        lsum += dx * dx + dy * dy + dz * dz + dw * dw;
        *(float4*)(qrow + f * 4) = e;
    }
#pragma unroll
    for (int off = 32; off; off >>= 1) lsum += __shfl_down(lsum, off);
    if ((tid & 63) == 0) red[tid >> 6] = lsum;
    __syncthreads();
    if (tid == 0) partial[blockIdx.x] = red[0] + red[1] + red[2] + red[3];
}

// ---------------------------------------------------------------------------
__global__ void k_loss(const float* __restrict__ partial, float* __restrict__ out_loss) {
    __shared__ float red[4];
    int tid = threadIdx.x;
    float s = partial[tid];
#pragma unroll
    for (int off = 32; off; off >>= 1) s += __shfl_down(s, off);
    if ((tid & 63) == 0) red[tid >> 6] = s;
    __syncthreads();
    if (tid == 0)
        out_loss[0] = (red[0] + red[1] + red[2] + red[3]) * (1.25f / 8388608.0f);
}

// ---------------------------------------------------------------------------
extern "C" void kernel_launch(void* const* d_in, const int* in_sizes, int n_in,
                              void* d_out, int out_size, void* d_ws, size_t ws_size,
                              hipStream_t stream) {
    const float* x   = (const float*)d_in[0];
    const float* W   = (const float*)d_in[1];
    const float* b   = (const float*)d_in[2];
    const float* emb = (const float*)d_in[3];

    float* out   = (float*)d_out;
    float* quant = out;                          // holds z, then quant
    float* oidx  = out + (size_t)TT * DD;
    float* oloss = oidx + TT;

    float* wsf     = (float*)d_ws;
    float* ee      = wsf;                        // [0, 1024)
    float* partial = wsf + 1024;                 // [1024, 1280)
    short* pemb    = (short*)(wsf + 1280);       // 262144 bf16 = 131072 f
    int*   g_nf    = (int*)(wsf + 132352);       // 1 int
    int*   g_list  = (int*)(wsf + 132353);       // 32768 ints
    float4* embP4  = (float4*)(wsf + 165124);    // 65536 float4 = 1 MB
    short* Wp      = (short*)(wsf + 427268);     // 196608 bf16 = 384 KB

    k_ee      <<<KK / 256, 256, 0, stream>>>(emb, ee, g_nf);
    k_pack    <<<128,      256, 0, stream>>>(emb, pemb, embP4);
    k_wpack   <<<32,       256, 0, stream>>>(W, Wp);
    k_proj    <<<TT / 32,  256, 0, stream>>>(x, Wp, b, quant);
    k_screen  <<<TT / 32,  256, 0, stream>>>(quant, pemb, ee, oidx);
    k_compact <<<TT / 256, 256, 0, stream>>>(oidx, g_nf, g_list);
    k_rescoreT<<<512,      256, 0, stream>>>(quant, embP4, ee, g_nf, g_list, oidx);
    k_gather  <<<TT / 128, 256, 0, stream>>>(quant, emb, oidx, partial);
    k_loss    <<<1,        256, 0, stream>>>(partial, oloss);
}

// Round 11
// 255.648 us; speedup vs baseline: 2.2228x; 1.4279x over previous
//
#include <hip/hip_runtime.h>
#include <hip/hip_bf16.h>

// x[32768,256] f32, W[256,256], b[256], emb[1024,256]
// d_out: quant[32768*256] | indices[32768] (as float) | loss[1]
//
// Pipeline (round-7 best-measured state, 259.6 us, + coalesced k_gather):
//   k_ee      : ee[n] = sum emb[n]^2 (+ zeroes the compaction counter)
//   k_pack    : emb -> bf16 packed in MFMA-fragment order (for k_screen) AND
//               emb -> fp32 transposed embP4[k4][n] (bit-exact, k_rescoreT).
//   k_proj    : z = x @ W^T + b via 3-way-split bf16 MFMA (err ~3e-7)
//   k_screen  : bf16 MFMA distance screen -> idx (+4096 flag if top-2 gap
//               < B_S). v3: NO cross-lane shuffle chains anywhere —
//               zz via LDS partials + EXACT butterfly-tree emulation
//               (bit-identical to the validated shfl tree); top-2 reduce via
//               LDS transpose + serial multiset scan (order-independent ->
//               identical values); A fragments in registers; B staged by
//               global_load_lds big phases; launch_bounds(256,1) so nothing
//               spills. Scores within <=1 ulp of the validated kernel (accA+
//               accB chain split) — far inside the B_S flag margin.
//   k_compact : ballot+atomic compaction of flagged token ids.
//   k_rescoreT: exact fp32 re-argmin over the worklist (validated chains).
//   k_gather  : quant = emb[idx] (in-place over z), loss partials.
//               ROUND-11: wave-per-token-row mapping — every load/store is a
//               1KB fully-coalesced wave access (old mapping produced 32B
//               segments). Loss partial reassociated (~1e-7, inside margin).
//   k_loss    : 1.25 * sum / (T*D)
//
// Numerics: reference dist = fl(fl(zz+ee[n]) - 2*dot) quantized to ulp(~256)
// ~3e-5. Screen score error sigma ~2.7e-5; B_S = 5e-4 >> 8*sigma + 2 ulp, so
// unflagged tokens have a guaranteed-unique exact argmin; flagged tokens get
// the full exact scan — the round-2/3 validated formula.
#define TT 32768
#define DD 256
#define KK 1024
#define B_S 5e-4f

typedef __attribute__((ext_vector_type(8)))  short bf16x8;
typedef __attribute__((ext_vector_type(4)))  short bf16x4s;
typedef __attribute__((ext_vector_type(16))) float f32x16;

static inline __device__ short f2bf(float v) {
    __hip_bfloat16 h = __float2bfloat16(v);
    return __builtin_bit_cast(short, h);
}
static inline __device__ float bf2f(short s) {
    __hip_bfloat16 h = __builtin_bit_cast(__hip_bfloat16, s);
    return __bfloat162float(h);
}

// async global->LDS, 16B per lane. LDS dest wave-uniform; global src per-lane.
static inline __device__ void gload16(const void* g, void* l) {
    __builtin_amdgcn_global_load_lds(
        (const __attribute__((address_space(1))) void*)g,
        (__attribute__((address_space(3))) void*)l,
        16, 0, 0);
}

// ---------------------------------------------------------------------------
__global__ void k_ee(const float* __restrict__ emb, float* __restrict__ ee,
                     int* __restrict__ g_nf) {
    if (blockIdx.x == 0 && threadIdx.x == 0) g_nf[0] = 0;
    int n = blockIdx.x * 256 + threadIdx.x;
    if (n >= KK) return;
    const float4* r = (const float4*)(emb + (size_t)n * DD);
    float s = 0.f;
#pragma unroll
    for (int i = 0; i < DD / 4; ++i) {
        float4 v = r[i];
        s += v.x * v.x + v.y * v.y + v.z * v.z + v.w * v.w;
    }
    ee[n] = s;
}

// ---------------------------------------------------------------------------
// Pack emb as bf16 in MFMA-fragment order (pemb) and as fp32 transposed
// float4 blocks (embP4[k4*1024 + n] = emb[n][k4*4 .. +3], bit-exact).
// 16B unit u: lane=u&63, ks=(u>>6)&1, nb=(u>>7)&3, kbi=(u>>9)&7, nc=(u>>12)&7
// holds emb[nc*128 + nb*32 + (lane&31)][kbi*32 + ks*16 + (lane>>5)*8 .. +7]
__global__ void k_pack(const float* __restrict__ emb, short* __restrict__ pemb,
                       float4* __restrict__ embP4) {
    int u = blockIdx.x * 256 + threadIdx.x;
    int lane = u & 63;
    int ks  = (u >> 6) & 1, nb = (u >> 7) & 3;
    int kbi = (u >> 9) & 7, nc = (u >> 12) & 7;
    int n = nc * 128 + nb * 32 + (lane & 31);
    int k = kbi * 32 + ks * 16 + (lane >> 5) * 8;
    const float* src = emb + (size_t)n * DD + k;
    float4 v0 = *(const float4*)(src);
    float4 v1 = *(const float4*)(src + 4);
    bf16x8 hb = { f2bf(v0.x), f2bf(v0.y), f2bf(v0.z), f2bf(v0.w),
                  f2bf(v1.x), f2bf(v1.y), f2bf(v1.z), f2bf(v1.w) };
    *(bf16x8*)(pemb + (size_t)u * 8) = hb;
    embP4[(size_t)(k >> 2) * KK + n]       = v0;
    embP4[(size_t)((k >> 2) + 1) * KK + n] = v1;
}

// ---------------------------------------------------------------------------
// z = x @ W^T + b via 3-way split bf16 MFMA. 64 tokens x 256 outs per block.
#define PW 40   // bf16 row stride for 32-k tiles (80 B: 16B-aligned)

__launch_bounds__(256, 2)
__global__ void k_proj(const float* __restrict__ x, const float* __restrict__ W,
                       const float* __restrict__ bias, float* __restrict__ z) {
    __shared__ __align__(16) short Ax[3][64 * PW];    // 15 KB
    __shared__ __align__(16) short Bw[3][256 * PW];   // 60 KB
    const int tid = threadIdx.x;
    const int w = tid >> 6, lane = tid & 63;
    const int l31 = lane & 31, h = lane >> 5;
    const int t0 = blockIdx.x * 64;
    const int wt = (w & 1) * 32;        // wave token offset
    const int wc = (w >> 1) * 128;      // wave col offset

    f32x16 acc[4];
#pragma unroll
    for (int cb = 0; cb < 4; ++cb)
#pragma unroll
        for (int r = 0; r < 16; ++r) acc[cb][r] = 0.f;

    for (int kb = 0; kb < DD; kb += 32) {
        __syncthreads();
        // x tile 64x32 -> 3-way split
#pragma unroll
        for (int j = 0; j < 2; ++j) {
            int idx = j * 256 + tid, row = idx >> 3, c4 = idx & 7;
            float4 v = *(const float4*)(x + (size_t)(t0 + row) * DD + kb + c4 * 4);
            float e[4] = {v.x, v.y, v.z, v.w};
            bf16x4s s1, s2, s3;
#pragma unroll
            for (int q = 0; q < 4; ++q) {
                short h1 = f2bf(e[q]); float r1 = e[q] - bf2f(h1);
                short h2 = f2bf(r1);   float r2 = r1 - bf2f(h2);
                short h3 = f2bf(r2);
                s1[q] = h1; s2[q] = h2; s3[q] = h3;
            }
            int a = row * PW + c4 * 4;
            *(bf16x4s*)&Ax[0][a] = s1; *(bf16x4s*)&Ax[1][a] = s2; *(bf16x4s*)&Ax[2][a] = s3;
        }
        // W tile 256x32 -> 3-way split
#pragma unroll
        for (int j = 0; j < 8; ++j) {
            int idx = j * 256 + tid, row = idx >> 3, c4 = idx & 7;
            float4 v = *(const float4*)(W + (size_t)row * DD + kb + c4 * 4);
            float e[4] = {v.x, v.y, v.z, v.w};
            bf16x4s s1, s2, s3;
#pragma unroll
            for (int q = 0; q < 4; ++q) {
                short h1 = f2bf(e[q]); float r1 = e[q] - bf2f(h1);
                short h2 = f2bf(r1);   float r2 = r1 - bf2f(h2);
                short h3 = f2bf(r2);
                s1[q] = h1; s2[q] = h2; s3[q] = h3;
            }
            int a = row * PW + c4 * 4;
            *(bf16x4s*)&Bw[0][a] = s1; *(bf16x4s*)&Bw[1][a] = s2; *(bf16x4s*)&Bw[2][a] = s3;
        }
        __syncthreads();
#pragma unroll
        for (int ks = 0; ks < 2; ++ks) {
            int ao = (wt + l31) * PW + ks * 16 + h * 8;
            bf16x8 a1 = *(bf16x8*)&Ax[0][ao];
            bf16x8 a2 = *(bf16x8*)&Ax[1][ao];
            bf16x8 a3 = *(bf16x8*)&Ax[2][ao];
#pragma unroll
            for (int cb = 0; cb < 4; ++cb) {
                int bo = (wc + cb * 32 + l31) * PW + ks * 16 + h * 8;
                bf16x8 b1 = *(bf16x8*)&Bw[0][bo];
                bf16x8 b2 = *(bf16x8*)&Bw[1][bo];
                bf16x8 b3 = *(bf16x8*)&Bw[2][bo];
                // small terms first for accumulation accuracy
                acc[cb] = __builtin_amdgcn_mfma_f32_32x32x16_bf16(a1, b3, acc[cb], 0, 0, 0);
                acc[cb] = __builtin_amdgcn_mfma_f32_32x32x16_bf16(a2, b2, acc[cb], 0, 0, 0);
                acc[cb] = __builtin_amdgcn_mfma_f32_32x32x16_bf16(a3, b1, acc[cb], 0, 0, 0);
                acc[cb] = __builtin_amdgcn_mfma_f32_32x32x16_bf16(a1, b2, acc[cb], 0, 0, 0);
                acc[cb] = __builtin_amdgcn_mfma_f32_32x32x16_bf16(a2, b1, acc[cb], 0, 0, 0);
                acc[cb] = __builtin_amdgcn_mfma_f32_32x32x16_bf16(a1, b1, acc[cb], 0, 0, 0);
            }
        }
    }
    // epilogue: C/D layout col=lane&31, row=(r&3)+8*(r>>2)+4*(lane>>5)
#pragma unroll
    for (int cb = 0; cb < 4; ++cb) {
        int col = wc + cb * 32 + l31;
        float bc = bias[col];
#pragma unroll
        for (int r = 0; r < 16; ++r) {
            int row = (r & 3) + 8 * (r >> 2) + 4 * h;
            z[(size_t)(t0 + wt + row) * DD + col] = acc[cb][r] + bc;
        }
    }
}

// ---------------------------------------------------------------------------
// bf16 MFMA screening v3 — no shuffle chains, no spills.
#define SW 264   // A_s row stride (bf16 elems)

__launch_bounds__(256, 1)
__global__ void k_screen(const float* __restrict__ z, const short* __restrict__ pemb,
                         const float* __restrict__ ee_g, float* __restrict__ out_idx) {
    __shared__ __align__(16) char smem[65536];   // A_s+zpart (init) / B dbuf / ent (epi)
    __shared__ float ee_s[1024];
    __shared__ float zzs[64];

    short* A_s   = (short*)smem;                 // 64*264*2 = 33792 B
    float* zpart = (float*)(smem + 33792);       // 64*65*4  = 16640 B
    const int tid = threadIdx.x;
    const int w = tid >> 6, lane = tid & 63;
    const int l31 = lane & 31, h = lane >> 5;
    const int t0 = blockIdx.x * 64;
    const int wr = (w >> 1) * 32;   // token-row group
    const int hw = w & 1;           // 32-code sub-block parity

#pragma unroll
    for (int i = 0; i < 4; ++i) ee_s[i * 256 + tid] = ee_g[i * 256 + tid];

    // A init: z tile -> bf16 LDS + per-lane zz partials (NO shuffle chains)
#pragma unroll
    for (int i = 0; i < 16; ++i) {
        int tl = i * 4 + w;
        float4 v = *(const float4*)(z + (size_t)(t0 + tl) * DD + lane * 4);
        float sq = v.x * v.x + v.y * v.y + v.z * v.z + v.w * v.w;  // verbatim expr
        zpart[tl * 65 + lane] = sq;
        bf16x4s hb = {f2bf(v.x), f2bf(v.y), f2bf(v.z), f2bf(v.w)};
        *(bf16x4s*)&A_s[tl * SW + lane * 4] = hb;
    }
    __syncthreads();

    // zz: EXACT butterfly-tree emulation of the validated shfl_xor(32..1)
    // reduce — same bracketing, bit-identical result, no latency chains.
    if (tid < 64) {
        float t_[32];
#pragma unroll
        for (int l = 0; l < 32; ++l) t_[l] = zpart[tid * 65 + l] + zpart[tid * 65 + l + 32];
#pragma unroll
        for (int l = 0; l < 16; ++l) t_[l] = t_[l] + t_[l + 16];
#pragma unroll
        for (int l = 0; l < 8; ++l)  t_[l] = t_[l] + t_[l + 8];
#pragma unroll
        for (int l = 0; l < 4; ++l)  t_[l] = t_[l] + t_[l + 4];
#pragma unroll
        for (int l = 0; l < 2; ++l)  t_[l] = t_[l] + t_[l + 2];
        zzs[tid] = t_[0] + t_[1];
    }

    // hoist all A fragments (full K) into registers: af[kbi*2+ks]
    bf16x8 af[16];
#pragma unroll
    for (int kbi = 0; kbi < 8; ++kbi)
#pragma unroll
        for (int ks = 0; ks < 2; ++ks)
            af[kbi * 2 + ks] = *(bf16x8*)&A_s[(wr + l31) * SW + kbi * 32 + ks * 16 + h * 8];
    __syncthreads();   // A_s/zpart dead -> smem becomes B double buffer; zzs ready

    // hoist zz for this lane's 16 output rows
    float zf[16];
#pragma unroll
    for (int r = 0; r < 16; ++r) zf[r] = zzs[wr + (r & 3) + 8 * (r >> 2) + 4 * h];

    // stage phase 0 into buf 0 (wave w stages its 1KB slice of each 4KB piece)
    const char* pB = (const char*)pemb;
#pragma unroll
    for (int j = 0; j < 8; ++j)
        gload16(pB + j * 8192 + w * 1024 + lane * 16, smem + j * 4096 + w * 1024);

    float bestv[16], secv[16]; int besti[16];
#pragma unroll
    for (int r = 0; r < 16; ++r) { bestv[r] = 1e30f; secv[r] = 1e30f; besti[r] = 0; }

    for (int ph = 0; ph < 16; ++ph) {
        const int buf = ph & 1;
        char* Bb = smem + buf * 32768;
        asm volatile("s_waitcnt vmcnt(0)" ::: "memory");
        __syncthreads();   // this phase staged; other buffer free for reuse
        if (ph < 15) {
            const int nn = ph + 1;
            const char* src = pB + (size_t)(nn >> 1) * 65536 + (nn & 1) * 4096;
            char* dst = smem + (buf ^ 1) * 32768;
#pragma unroll
            for (int j = 0; j < 8; ++j)
                gload16(src + j * 8192 + w * 1024 + lane * 16, dst + j * 4096 + w * 1024);
        }
        // compute: two independent 8-MFMA chains (kbi 0-3 -> accA, 4-7 -> accB)
        f32x16 accA, accB;
#pragma unroll
        for (int r = 0; r < 16; ++r) { accA[r] = 0.f; accB[r] = 0.f; }
#pragma unroll
        for (int kbi = 0; kbi < 4; ++kbi) {
            bf16x8 a0b = *(bf16x8*)(Bb + kbi * 4096 + (hw * 2 + 0) * 1024 + lane * 16);
            bf16x8 a1b = *(bf16x8*)(Bb + kbi * 4096 + (hw * 2 + 1) * 1024 + lane * 16);
            bf16x8 b0b = *(bf16x8*)(Bb + (kbi + 4) * 4096 + (hw * 2 + 0) * 1024 + lane * 16);
            bf16x8 b1b = *(bf16x8*)(Bb + (kbi + 4) * 4096 + (hw * 2 + 1) * 1024 + lane * 16);
            accA = __builtin_amdgcn_mfma_f32_32x32x16_bf16(af[kbi * 2 + 0], a0b, accA, 0, 0, 0);
            accB = __builtin_amdgcn_mfma_f32_32x32x16_bf16(af[(kbi + 4) * 2 + 0], b0b, accB, 0, 0, 0);
            accA = __builtin_amdgcn_mfma_f32_32x32x16_bf16(af[kbi * 2 + 1], a1b, accA, 0, 0, 0);
            accB = __builtin_amdgcn_mfma_f32_32x32x16_bf16(af[(kbi + 4) * 2 + 1], b1b, accB, 0, 0, 0);
        }
        // fold: s = fl(fl(zz+ee) - 2*(accA+accB)), track top-2 + best index
        {
            int n = (ph >> 1) * 128 + (ph & 1) * 64 + hw * 32 + l31;
            float en = ee_s[n];
#pragma unroll
            for (int r = 0; r < 16; ++r) {
                float u = zf[r] + en;
                float d = accA[r] + accB[r];
                float sc = fmaf(-2.f, d, u);
                if (sc < bestv[r])      { secv[r] = bestv[r]; bestv[r] = sc; besti[r] = n; }
                else if (sc < secv[r])  { secv[r] = sc; }
            }
        }
    }

    // epilogue: LDS transpose + serial multiset scan (lex-min + min-2 are
    // order-independent -> identical values to the validated shfl reduce).
    __syncthreads();   // all B reads done -> smem reusable
    float* entV = (float*)smem;          // [64][66] f32 = 16896 B
    float* entS = entV + 4224;           // [64][66]
    int*   entI = (int*)(entV + 8448);   // [64][66]
    const int slot = hw * 32 + l31;
#pragma unroll
    for (int r = 0; r < 16; ++r) {
        int tr = wr + (r & 3) + 8 * (r >> 2) + 4 * h;
        entV[tr * 66 + slot] = bestv[r];
        entS[tr * 66 + slot] = secv[r];
        entI[tr * 66 + slot] = besti[r];
    }
    __syncthreads();
    if (tid < 64) {
        float bv = entV[tid * 66 + 0];
        float sv = entS[tid * 66 + 0];
        int   bi = entI[tid * 66 + 0];
        for (int e = 1; e < 64; ++e) {
            float v  = entV[tid * 66 + e];
            float s2 = entS[tid * 66 + e];
            int   i  = entI[tid * 66 + e];
            float mx = fmaxf(bv, v);
            sv = fminf(fminf(sv, s2), mx);
            if (v < bv || (v == bv && i < bi)) { bv = v; bi = i; }
        }
        float flag = ((sv - bv) < B_S) ? 4096.0f : 0.0f;
        out_idx[t0 + tid] = (float)bi + flag;
    }
}

// ---------------------------------------------------------------------------
// Compact flagged token ids into a global worklist (order-independent result).
__global__ void k_compact(const float* __restrict__ out_idx, int* __restrict__ g_nf,
                          int* __restrict__ g_list) {
    __shared__ int wbase[4];
    __shared__ int bbase;
    const int tid = threadIdx.x;
    const int t = blockIdx.x * 256 + tid;
    const int wid = tid >> 6, lane = tid & 63;
    bool fl = out_idx[t] >= 4096.0f;
    unsigned long long m = __ballot(fl);
    if (lane == 0) wbase[wid] = __popcll(m);
    __syncthreads();
    if (tid == 0) {
        int s = 0;
#pragma unroll
        for (int i = 0; i < 4; ++i) { int c = wbase[i]; wbase[i] = s; s += c; }
        bbase = atomicAdd(g_nf, s);
    }
    __syncthreads();
    if (fl) {
        int rank = __popcll(m & ((1ull << lane) - 1ull));
        g_list[bbase + wbase[wid] + rank] = t;
    }
}

// ---------------------------------------------------------------------------
// Exact fp32 re-argmin over the worklist, 8 tokens/batch, grid-stride.
// (validated round-5 structure, bit-exact chains)
#define RB 8    // tokens per batch (validated batch size)

__launch_bounds__(256, 2)
__global__ void k_rescoreT(const float* __restrict__ z, const float4* __restrict__ embP4,
                           const float* __restrict__ ee_g, const int* __restrict__ g_nf,
                           const int* __restrict__ g_list, float* __restrict__ out_idx) {
    __shared__ float zrows[RB][256];                 // 8 KB
    __shared__ float zz8[RB];
    __shared__ int   toks[RB];
    __shared__ float rv_s[RB][4]; __shared__ int ri_s[RB][4];
    const int tid = threadIdx.x;
    const int w = tid >> 6, lane = tid & 63;
    const int nf = g_nf[0];

    for (int base = blockIdx.x * RB; base < nf; base += gridDim.x * RB) {
        __syncthreads();   // previous batch fully done (zrows/toks reuse)
        if (tid < RB) toks[tid] = (base + tid < nf) ? g_list[base + tid] : -1;
        __syncthreads();
        // stage z rows (pad slots -> zeros: no stale-LDS reads)
#pragma unroll
        for (int qq = 0; qq < RB; ++qq) {
            int tok = toks[qq];
            zrows[qq][tid] = (tok >= 0) ? z[(size_t)tok * DD + tid] : 0.f;
        }
        __syncthreads();
        // zz — EXACT validated per-row arithmetic (wave w rows w, w+4)
        for (int qq = w; qq < RB; qq += 4) {
            float s = 0.f;
#pragma unroll
            for (int k = 0; k < 4; ++k) { float vv = zrows[qq][lane + 64 * k]; s += vv * vv; }
#pragma unroll
            for (int o = 32; o; o >>= 1) s += __shfl_xor(s, o);
            if (lane == 0) zz8[qq] = s;
        }
        __syncthreads();   // zz8 ready

        // hoisted ee for this thread's 4 codes (same loaded values as before)
        float en4[4];
#pragma unroll
        for (int p = 0; p < 4; ++p) en4[p] = ee_g[p * 256 + tid];

        float d[4][RB];
#pragma unroll
        for (int p = 0; p < 4; ++p)
#pragma unroll
            for (int q = 0; q < RB; ++q) d[p][q] = 0.f;

        // ping-pong buffers: eX = 4 coalesced global float4, zX = 8 LDS bcast
        float4 eA[4], eB[4], zA[RB], zB[RB];
#pragma unroll
        for (int p = 0; p < 4; ++p) eA[p] = embP4[(size_t)0 * KK + p * 256 + tid];
#pragma unroll
        for (int q = 0; q < RB; ++q) zA[q] = *(const float4*)&zrows[q][0];

        for (int k4 = 0; k4 < 64; k4 += 2) {
            // issue k4+1 into B (always valid: k4+1 <= 63)
#pragma unroll
            for (int p = 0; p < 4; ++p) eB[p] = embP4[(size_t)(k4 + 1) * KK + p * 256 + tid];
#pragma unroll
            for (int q = 0; q < RB; ++q) zB[q] = *(const float4*)&zrows[q][(k4 + 1) * 4];
            // compute k4 with A — EXACT chains: k4 ascending, x/y/z/w
#pragma unroll
            for (int p = 0; p < 4; ++p)
#pragma unroll
                for (int q = 0; q < RB; ++q) {
                    d[p][q] = fmaf(eA[p].x, zA[q].x, d[p][q]);
                    d[p][q] = fmaf(eA[p].y, zA[q].y, d[p][q]);
                    d[p][q] = fmaf(eA[p].z, zA[q].z, d[p][q]);
                    d[p][q] = fmaf(eA[p].w, zA[q].w, d[p][q]);
                }
            // issue k4+2 into A (guarded)
            if (k4 < 62) {
#pragma unroll
                for (int p = 0; p < 4; ++p) eA[p] = embP4[(size_t)(k4 + 2) * KK + p * 256 + tid];
#pragma unroll
                for (int q = 0; q < RB; ++q) zA[q] = *(const float4*)&zrows[q][(k4 + 2) * 4];
            }
            // compute k4+1 with B
#pragma unroll
            for (int p = 0; p < 4; ++p)
#pragma unroll
                for (int q = 0; q < RB; ++q) {
                    d[p][q] = fmaf(eB[p].x, zB[q].x, d[p][q]);
                    d[p][q] = fmaf(eB[p].y, zB[q].y, d[p][q]);
                    d[p][q] = fmaf(eB[p].z, zB[q].z, d[p][q]);
                    d[p][q] = fmaf(eB[p].w, zB[q].w, d[p][q]);
                }
        }

        // fold: p ascending (= n ascending per thread), then q — verbatim
        float bv[RB]; int bi[RB];
#pragma unroll
        for (int q = 0; q < RB; ++q) { bv[q] = 1e30f; bi[q] = 0; }
#pragma unroll
        for (int p = 0; p < 4; ++p) {
            const int n = p * 256 + tid;
#pragma unroll
            for (int q = 0; q < RB; ++q) {
                float u = zz8[q] + en4[p];         // fl(zz+ee[n])
                float s = fmaf(-2.f, d[p][q], u);  // fl(u - 2*dot)
                if (s < bv[q]) { bv[q] = s; bi[q] = n; }
            }
        }
        // per-token block reduce: lexicographic (value, index) first-min
        for (int q = 0; q < RB; ++q) {
            float v = bv[q]; int i = bi[q];
#pragma unroll
            for (int o = 1; o < 64; o <<= 1) {
                float ov = __shfl_xor(v, o); int oi = __shfl_xor(i, o);
                if (ov < v || (ov == v && oi < i)) { v = ov; i = oi; }
            }
            if (lane == 0) { rv_s[q][w] = v; ri_s[q][w] = i; }
        }
        __syncthreads();
        if (tid < RB) {
            int tk = toks[tid];
            if (tk >= 0) {
                float fv = rv_s[tid][0]; int fi = ri_s[tid][0];
#pragma unroll
                for (int ww = 1; ww < 4; ++ww) {
                    if (rv_s[tid][ww] < fv || (rv_s[tid][ww] == fv && ri_s[tid][ww] < fi)) {
                        fv = rv_s[tid][ww]; fi = ri_s[tid][ww];
                    }
                }
                out_idx[tk] = (float)fi;
            }
        }
    }
}

// ---------------------------------------------------------------------------
// quant = emb[idx] + loss partials. Wave-per-token-row: lane l owns float4 l
// of the 256-float row -> every load/store is a 1KB fully-coalesced wave
// access (old 2-thread/token interleave produced 32B segments). Per-lane
// accumulation across the wave's 32 tokens, one wave reduce at the end
// (loss reassociation ~1e-7, far inside the passing margin).
__global__ void k_gather(float* __restrict__ zq, const float* __restrict__ emb,
                         const float* __restrict__ out_idx, float* __restrict__ partial) {
    __shared__ float red[4];
    const int tid = threadIdx.x;
    const int w = tid >> 6, lane = tid & 63;
    const int t0 = blockIdx.x * 128 + w * 32;
    float lsum = 0.f;
#pragma unroll 4
    for (int i = 0; i < 32; ++i) {
        const int t = t0 + i;
        int widx = (int)out_idx[t];
        widx = min(max(widx, 0), KK - 1);
        float4 e  = *(const float4*)(emb + (size_t)widx * DD + lane * 4);
        float4 zv = *(const float4*)(zq  + (size_t)t    * DD + lane * 4);
        float dx = e.x - zv.x, dy = e.y - zv.y, dz = e.z - zv.z, dw = e.w - zv.w;
        lsum += dx * dx + dy * dy + dz * dz + dw * dw;
        *(float4*)(zq + (size_t)t * DD + lane * 4) = e;
    }
#pragma unroll
    for (int off = 32; off; off >>= 1) lsum += __shfl_down(lsum, off);
    if (lane == 0) red[w] = lsum;
    __syncthreads();
    if (tid == 0) partial[blockIdx.x] = red[0] + red[1] + red[2] + red[3];
}

// ---------------------------------------------------------------------------
__global__ void k_loss(const float* __restrict__ partial, float* __restrict__ out_loss) {
    __shared__ float red[4];
    int tid = threadIdx.x;
    float s = partial[tid];
#pragma unroll
    for (int off = 32; off; off >>= 1) s += __shfl_down(s, off);
    if ((tid & 63) == 0) red[tid >> 6] = s;
    __syncthreads();
    if (tid == 0)
        out_loss[0] = (red[0] + red[1] + red[2] + red[3]) * (1.25f / 8388608.0f);
}

// ---------------------------------------------------------------------------
extern "C" void kernel_launch(void* const* d_in, const int* in_sizes, int n_in,
                              void* d_out, int out_size, void* d_ws, size_t ws_size,
                              hipStream_t stream) {
    const float* x   = (const float*)d_in[0];
    const float* W   = (const float*)d_in[1];
    const float* b   = (const float*)d_in[2];
    const float* emb = (const float*)d_in[3];

    float* out   = (float*)d_out;
    float* quant = out;                          // holds z, then quant
    float* oidx  = out + (size_t)TT * DD;
    float* oloss = oidx + TT;

    float* wsf     = (float*)d_ws;
    float* ee      = wsf;                        // [0, 1024)
    float* partial = wsf + 1024;                 // [1024, 1280)
    short* pemb    = (short*)(wsf + 1280);       // 262144 bf16 = 131072 f
    int*   g_nf    = (int*)(wsf + 132352);       // 1 int
    int*   g_list  = (int*)(wsf + 132353);       // 32768 ints
    float4* embP4  = (float4*)(wsf + 165124);    // 65536 float4 = 1 MB (16B-aligned)

    k_ee      <<<KK / 256, 256, 0, stream>>>(emb, ee, g_nf);
    k_pack    <<<128,      256, 0, stream>>>(emb, pemb, embP4);
    k_proj    <<<TT / 64,  256, 0, stream>>>(x, W, b, quant);
    k_screen  <<<TT / 64,  256, 0, stream>>>(quant, pemb, ee, oidx);
    k_compact <<<TT / 256, 256, 0, stream>>>(oidx, g_nf, g_list);
    k_rescoreT<<<512,      256, 0, stream>>>(quant, embP4, ee, g_nf, g_list, oidx);
    k_gather  <<<TT / 128, 256, 0, stream>>>(quant, emb, oidx, partial);
    k_loss    <<<1,        256, 0, stream>>>(partial, oloss);
}